// Round 8
// baseline (284.986 us; speedup 1.0000x reference)
//
#include <hip/hip_runtime.h>
#include <hip/hip_bf16.h>
#include <math.h>

typedef __bf16 bf16;
typedef __attribute__((ext_vector_type(8))) __bf16 bf16x8;
typedef __attribute__((ext_vector_type(4))) __bf16 bf16x4;
typedef __attribute__((ext_vector_type(4))) float f32x4;

#define NHEAD 16
#define DKH 64
#define SEQ 2048
#define DMODEL 1024

// async 16B global->LDS (wave-uniform LDS base + lane*16, per-lane global src)
__device__ __forceinline__ void gl_lds16(const void* g, void* lds) {
  __builtin_amdgcn_global_load_lds(
      (const __attribute__((address_space(1))) unsigned int*)g,
      (__attribute__((address_space(3))) unsigned int*)lds, 16, 0, 0);
}

// one launch converting x + 4 weight matrices fp32->bf16 (4-elem units)
__global__ void cvt5_kernel(const float* __restrict__ x, const float* __restrict__ wq,
                            const float* __restrict__ wk, const float* __restrict__ wv,
                            const float* __restrict__ wo, bf16* __restrict__ xb,
                            bf16* __restrict__ wqb, bf16* __restrict__ wkb,
                            bf16* __restrict__ wvb, bf16* __restrict__ wob) {
  int i = blockIdx.x * blockDim.x + threadIdx.x;  // [0, 2097152)
  const float* src; bf16* dst; int li;
  if (i < 1048576)      { src = x;  dst = xb;  li = i; }
  else if (i < 1310720) { src = wq; dst = wqb; li = i - 1048576; }
  else if (i < 1572864) { src = wk; dst = wkb; li = i - 1310720; }
  else if (i < 1835008) { src = wv; dst = wvb; li = i - 1572864; }
  else                  { src = wo; dst = wob; li = i - 1835008; }
  float4 v = ((const float4*)src)[li];
  bf16x4 o = { (bf16)v.x, (bf16)v.y, (bf16)v.z, (bf16)v.w };
  ((bf16x4*)dst)[li] = o;
}

// swizzled LDS fragment read, 64-col tiles (8 granules): granule ^= row&7
__device__ __forceinline__ bf16x8 lds_frag(const bf16* T, int row, int gran) {
  return *(const bf16x8*)&T[row * 64 + ((gran ^ (row & 7)) << 3)];
}
// swizzled LDS fragment read, 32-col tiles (4 granules): granule ^= row&3
__device__ __forceinline__ bf16x8 lds_frag32(const bf16* T, int row, int gran) {
  return *(const bf16x8*)&T[row * 32 + ((gran ^ (row & 3)) << 3)];
}

// C[m,n] = sum_k A[m,k]*B[n,k]; A:[M,K], B:[N,K] bf16 row-major. BK=32,
// double-buffered 2-phase (stage next -> compute cur -> one barrier), 32 KB
// LDS -> 5 blocks/CU. MODE 0: fp32 C. MODE 3: fused QKV split.
template<int MODE>
__global__ __launch_bounds__(256, 5) void gemm_nt(const bf16* __restrict__ A,
                                                  const bf16* __restrict__ Bw,
                                                  float* __restrict__ Cf,
                                                  bf16* __restrict__ Cq,
                                                  bf16* __restrict__ Ck,
                                                  bf16* __restrict__ Cv,
                                                  int M, int N, int K) {
  __shared__ __attribute__((aligned(16))) bf16 As[2][128 * 32];
  __shared__ __attribute__((aligned(16))) bf16 Bs[2][128 * 32];
  const int t = threadIdx.x;
  const int w = t >> 6, l = t & 63;
  const int wr = w >> 1, wc = w & 1;
  // XCD-chunked swizzle (nwg divisible by 8): contiguous tile chunk per XCD
  const int lin = blockIdx.y * gridDim.x + blockIdx.x;
  const int cpx = (gridDim.x * gridDim.y) >> 3;
  const int swz = (lin & 7) * cpx + (lin >> 3);
  const int tm = (swz / gridDim.x) * 128, tn = (swz % gridDim.x) * 128;
  const int c16 = l & 15, g4 = l >> 4;
  const int srow = l >> 2;                       // 16 rows per gl_lds16
  const int sg = ((l & 3) ^ (srow & 3)) * 8;     // pre-swizzled src col (elems)

  f32x4 acc[4][4];
#pragma unroll
  for (int i = 0; i < 4; ++i)
#pragma unroll
    for (int j = 0; j < 4; ++j) acc[i][j] = f32x4{0.f, 0.f, 0.f, 0.f};

  auto stage = [&](int buf, int k0) {
#pragma unroll
    for (int c = 0; c < 2; ++c) {
      const int r0 = w * 32 + c * 16;  // wave-uniform segment base (16 rows)
      gl_lds16(A + (size_t)(tm + r0 + srow) * K + k0 + sg, &As[buf][r0 * 32]);
      gl_lds16(Bw + (size_t)(tn + r0 + srow) * K + k0 + sg, &Bs[buf][r0 * 32]);
    }
  };

  const int NK = K >> 5;
  stage(0, 0);
  __syncthreads();

  for (int kt = 0; kt < NK; ++kt) {
    const int cur = kt & 1;
    if (kt + 1 < NK) stage(cur ^ 1, (kt + 1) << 5);
    bf16x8 af[4], bfr[4];
#pragma unroll
    for (int i = 0; i < 4; ++i)
      af[i] = lds_frag32(As[cur], wr * 64 + i * 16 + c16, g4);
#pragma unroll
    for (int j = 0; j < 4; ++j)
      bfr[j] = lds_frag32(Bs[cur], wc * 64 + j * 16 + c16, g4);
    __builtin_amdgcn_s_setprio(1);
#pragma unroll
    for (int i = 0; i < 4; ++i)
#pragma unroll
      for (int j = 0; j < 4; ++j)
        acc[i][j] = __builtin_amdgcn_mfma_f32_16x16x32_bf16(af[i], bfr[j], acc[i][j], 0, 0, 0);
    __builtin_amdgcn_s_setprio(0);
    __syncthreads();  // drains prefetch vmcnt + everyone done reading cur
  }

  const int which = tn >> 10;  // MODE 3: whole block in one of q/k/v
#pragma unroll
  for (int i = 0; i < 4; ++i) {
    const int row0 = tm + wr * 64 + i * 16 + g4 * 4;
#pragma unroll
    for (int j = 0; j < 4; ++j) {
      const int col = tn + wc * 64 + j * 16 + c16;
      if (MODE == 0) {
#pragma unroll
        for (int r = 0; r < 4; ++r) Cf[(size_t)(row0 + r) * N + col] = acc[i][j][r];
      } else {
        const int lc = col & 1023;
        if (which == 2) {  // V: transposed per head
          const int bb = row0 >> 11, s = row0 & 2047;
          const int hh = lc >> 6, dk = lc & 63;
          bf16x4 o = { (bf16)acc[i][j][0], (bf16)acc[i][j][1],
                       (bf16)acc[i][j][2], (bf16)acc[i][j][3] };
          *(bf16x4*)&Cv[((size_t)(bb * NHEAD + hh) * DKH + dk) * SEQ + s] = o;
        } else {
          bf16* dst = which ? Ck : Cq;
#pragma unroll
          for (int r = 0; r < 4; ++r)
            dst[(size_t)(row0 + r) * DMODEL + lc] = (bf16)acc[i][j][r];
        }
      }
    }
  }
}

__device__ __forceinline__ f32x4 vmax4(f32x4 a, f32x4 b) {
  return f32x4{ fmaxf(a[0], b[0]), fmaxf(a[1], b[1]),
                fmaxf(a[2], b[2]), fmaxf(a[3], b[3]) };
}

// Flash attention, causal. 512 blocks x 512 threads (8 waves). Waves split in
// two groups: A (w<4) handles even 64-kv subtiles, B odd, of a staged 128-kv
// tile. Each block: q-tile pair (31-pr, pr) -> uniformly 17 iterations.
// Per-q-tile merge of (m,l,acc) through LDS (B -> A). Swapped QK^T, in-lane
// softmax, MFMA row-sum, defer-max.
__global__ __launch_bounds__(512, 4) void attn_kernel(const bf16* __restrict__ qb,
                                                      const bf16* __restrict__ kb,
                                                      const bf16* __restrict__ vT,
                                                      bf16* __restrict__ ob) {
  __shared__ __attribute__((aligned(16))) bf16 Ke[2][64 * 64];
  __shared__ __attribute__((aligned(16))) bf16 Ko[2][64 * 64];
  __shared__ __attribute__((aligned(16))) bf16 Ve[2][64 * 64];
  __shared__ __attribute__((aligned(16))) bf16 Vo[2][64 * 64];
  __shared__ __attribute__((aligned(16))) bf16 Pb[8][16 * 64];  // P + merge area
  const int w = threadIdx.x >> 6, l = threadIdx.x & 63;
  const int g = w >> 2, wq = w & 3;
  // bijective XCD chunking: 512 blocks, 64 consecutive work-items per XCD
  const int lin = blockIdx.x;
  const int swz = (lin & 7) * 64 + (lin >> 3);
  const int pr = swz & 15, h = (swz >> 4) & 15, b = swz >> 8;
  const int qtA = 31 - pr, qtB = pr;
  const int c16 = l & 15, g4 = l >> 4, r8 = l >> 3;
  const int sg = ((l & 7) ^ (r8 & 7)) * 8;  // pre-swizzled src col (elems)

  const float SC2 = 0.125f * 1.44269504089f;  // 1/sqrt(dk) * log2(e)
  const float THR = 8.0f / SC2;               // defer-max threshold (raw scores)

  const bf16 oneb = (bf16)1.0f;
  const bf16x8 ones = { oneb, oneb, oneb, oneb, oneb, oneb, oneb, oneb };

  const bf16* kbase = kb + (size_t)b * SEQ * DMODEL + h * DKH;
  const bf16* vbase = vT + (size_t)(b * NHEAD + h) * DKH * SEQ;

  // Q fragments (B-operand) for both q-tiles: row = qt*64 + wq*16 + c16
  bf16x8 qfA[2], qfB[2];
#pragma unroll
  for (int d = 0; d < 2; ++d) {
    qfA[d] = *(const bf16x8*)(qb + (size_t)(b * SEQ + qtA * 64 + wq * 16 + c16) * DMODEL +
                              h * DKH + d * 32 + g4 * 8);
    qfB[d] = *(const bf16x8*)(qb + (size_t)(b * SEQ + qtB * 64 + wq * 16 + c16) * DMODEL +
                              h * DKH + d * 32 + g4 * 8);
  }

  // stage a 128-kv tile (t128): 4 regions of 64x64, each wave does 8 rows each
  auto stage = [&](int buf, int t128) {
    const int kt0 = t128 * 128;
    const int row = w * 8;  // wave-uniform segment base
    gl_lds16(kbase + (size_t)(kt0 + row + r8) * DMODEL + sg, &Ke[buf][row * 64]);
    gl_lds16(kbase + (size_t)(kt0 + 64 + row + r8) * DMODEL + sg, &Ko[buf][row * 64]);
    gl_lds16(vbase + (size_t)(row + r8) * SEQ + kt0 + sg, &Ve[buf][row * 64]);
    gl_lds16(vbase + (size_t)(row + r8) * SEQ + kt0 + 64 + sg, &Vo[buf][row * 64]);
  };

  stage(0, 0);
  __syncthreads();

  float mm = -INFINITY;
  f32x4 lsum4 = f32x4{0.f, 0.f, 0.f, 0.f};
  f32x4 acc[4];
#pragma unroll
  for (int n = 0; n < 4; ++n) acc[n] = f32x4{0.f, 0.f, 0.f, 0.f};

  const int TA128 = (qtA + 2) >> 1;           // ceil((qtA+1)/2)
  const int TT128 = TA128 + ((qtB + 2) >> 1); // uniformly 17
  const int ql = wq * 16 + c16;               // q row local to 64-tile

  for (int tt = 0; tt < TT128; ++tt) {
    const int cur = tt & 1;
    if (tt + 1 < TT128)
      stage(cur ^ 1, (tt + 1 < TA128) ? tt + 1 : tt + 1 - TA128);
    const bool pA = tt < TA128;
    const int t_in = pA ? tt : tt - TA128;
    const int qt = pA ? qtA : qtB;
    const int kt64 = 2 * t_in + g;  // this group's 64-kv subtile index

    if (kt64 <= qt) {
      const bf16* Kl = g ? &Ko[cur][0] : &Ke[cur][0];
      const bf16* Vl = g ? &Vo[cur][0] : &Ve[cur][0];
      const bf16x8 q0 = pA ? qfA[0] : qfB[0];
      const bf16x8 q1 = pA ? qfA[1] : qfB[1];

      // ---- QK^T swapped (raw): s[j] rows kv = j*16+g4*4+r, cols q = c16
      f32x4 s[4];
      __builtin_amdgcn_s_setprio(1);
#pragma unroll
      for (int j = 0; j < 4; ++j) {
        bf16x8 kf0 = lds_frag(Kl, j * 16 + c16, g4);
        bf16x8 kf1 = lds_frag(Kl, j * 16 + c16, 4 + g4);
        f32x4 c = f32x4{0.f, 0.f, 0.f, 0.f};
        c = __builtin_amdgcn_mfma_f32_16x16x32_bf16(kf0, q0, c, 0, 0, 0);
        c = __builtin_amdgcn_mfma_f32_16x16x32_bf16(kf1, q1, c, 0, 0, 0);
        s[j] = c;
      }
      __builtin_amdgcn_s_setprio(0);
      if (kt64 == qt) {  // diagonal subtile
#pragma unroll
        for (int j = 0; j < 4; ++j)
#pragma unroll
          for (int r = 0; r < 4; ++r)
            if (j * 16 + g4 * 4 + r > ql) s[j][r] = -INFINITY;
      }
      // ---- tile max of the 16 in-lane scores + 2 shfl
      f32x4 t01 = vmax4(s[0], s[1]);
      f32x4 t23 = vmax4(s[2], s[3]);
      f32x4 tv = vmax4(t01, t23);
      float v = fmaxf(fmaxf(tv[0], tv[1]), fmaxf(tv[2], tv[3]));
      v = fmaxf(v, __shfl_xor(v, 16));
      v = fmaxf(v, __shfl_xor(v, 32));
      // ---- defer-max: skip rescale when bounded (p <= 2^8)
      if (!__all(v <= mm + THR)) {
        const float mn = fmaxf(mm, v);
        const float scl = __builtin_amdgcn_exp2f(SC2 * (mm - mn));
        float sc4[4];
#pragma unroll
        for (int r = 0; r < 4; ++r) sc4[r] = __shfl(scl, g4 * 4 + r);
#pragma unroll
        for (int n = 0; n < 4; ++n)
#pragma unroll
          for (int r = 0; r < 4; ++r) acc[n][r] *= sc4[r];
#pragma unroll
        for (int r = 0; r < 4; ++r) lsum4[r] *= sc4[r];
        mm = mn;
      }
      const float nb = SC2 * mm;
      // ---- exp + spill P (b64 per 4 consecutive kv)
      bf16* P = &Pb[w][0];
#pragma unroll
      for (int j = 0; j < 4; ++j) {
        bf16x4 pk;
#pragma unroll
        for (int r = 0; r < 4; ++r)
          pk[r] = (bf16)__builtin_amdgcn_exp2f(fmaf(s[j][r], SC2, -nb));
        const int col = j * 16 + g4 * 4;
        *(bf16x4*)&P[c16 * 64 + (((col >> 3) ^ (c16 & 7)) << 3) + (col & 7)] = pk;
      }
      // ---- PV + row-sum via MFMA
      bf16x8 pa0 = lds_frag(P, c16, g4);
      bf16x8 pa1 = lds_frag(P, c16, 4 + g4);
      __builtin_amdgcn_s_setprio(1);
#pragma unroll
      for (int n = 0; n < 4; ++n) {
        bf16x8 vf0 = lds_frag(Vl, n * 16 + c16, g4);
        bf16x8 vf1 = lds_frag(Vl, n * 16 + c16, 4 + g4);
        acc[n] = __builtin_amdgcn_mfma_f32_16x16x32_bf16(pa0, vf0, acc[n], 0, 0, 0);
        acc[n] = __builtin_amdgcn_mfma_f32_16x16x32_bf16(pa1, vf1, acc[n], 0, 0, 0);
      }
      lsum4 = __builtin_amdgcn_mfma_f32_16x16x32_bf16(pa0, ones, lsum4, 0, 0, 0);
      lsum4 = __builtin_amdgcn_mfma_f32_16x16x32_bf16(pa1, ones, lsum4, 0, 0, 0);
      __builtin_amdgcn_s_setprio(0);
    }

    const bool mergeA = (tt == TA128 - 1);
    const bool mergeB = (tt == TT128 - 1);
    if (mergeA || mergeB) {
      const int qb0 = (mergeA ? qtA : qtB) * 64;
      __syncthreads();  // all compute done; P slots free for merge reuse
      float* ml = (float*)&Pb[wq][0];   // [0..15]=mB per q-row, [16..31]=lB
      bf16* xa = &Pb[4 + wq][0];        // accB bf16 [16 q][64 cols]
      if (g == 1) {
        if (g4 == 0) ml[c16] = mm;
        if (c16 == 0) {
#pragma unroll
          for (int r = 0; r < 4; ++r) ml[16 + g4 * 4 + r] = lsum4[r];
        }
#pragma unroll
        for (int n = 0; n < 4; ++n)
#pragma unroll
          for (int r = 0; r < 4; ++r)
            xa[(g4 * 4 + r) * 64 + n * 16 + c16] = (bf16)acc[n][r];
      }
      __syncthreads();  // B's state visible
      if (g == 0) {
#pragma unroll
        for (int r = 0; r < 4; ++r) {
          const int q = g4 * 4 + r;
          const float mA = __shfl(mm, q);
          const float mB = ml[q];
          const float lB = ml[16 + q];
          const float mt = fmaxf(mA, mB);
          const float fA = __builtin_amdgcn_exp2f(SC2 * (mA - mt));
          const float fB = __builtin_amdgcn_exp2f(SC2 * (mB - mt));
          const float inv = 1.f / (lsum4[r] * fA + lB * fB);
#pragma unroll
          for (int n = 0; n < 4; ++n) {
            const float accB = (float)xa[q * 64 + n * 16 + c16];
            const float o = (acc[n][r] * fA + accB * fB) * inv;
            ob[(size_t)(b * SEQ + qb0 + wq * 16 + q) * DMODEL +
               h * DKH + n * 16 + c16] = (bf16)o;
          }
        }
      }
      // reset both groups for next q-tile
      mm = -INFINITY;
      lsum4 = f32x4{0.f, 0.f, 0.f, 0.f};
#pragma unroll
      for (int n = 0; n < 4; ++n) acc[n] = f32x4{0.f, 0.f, 0.f, 0.f};
    }
    __syncthreads();  // protects P rewrite + dbuf flip (also after merge reads)
  }
}

extern "C" void kernel_launch(void* const* d_in, const int* in_sizes, int n_in,
                              void* d_out, int out_size, void* d_ws, size_t ws_size,
                              hipStream_t stream) {
  const float* x  = (const float*)d_in[0];
  const float* Wq = (const float*)d_in[1];
  const float* Wk = (const float*)d_in[2];
  const float* Wv = (const float*)d_in[3];
  const float* Wo = (const float*)d_in[4];
  float* out = (float*)d_out;
  char* ws = (char*)d_ws;
  const size_t MB = (size_t)1 << 20;

  // wqb/wkb/wvb contiguous -> one [3072][1024] weight matrix for fused QKV
  bf16* xb   = (bf16*)(ws + 0 * MB);   // 8MB
  bf16* wqb  = (bf16*)(ws + 8 * MB);   // 2MB
  bf16* wkb  = (bf16*)(ws + 10 * MB);  // 2MB
  bf16* wvb  = (bf16*)(ws + 12 * MB);  // 2MB
  bf16* wob  = (bf16*)(ws + 14 * MB);  // 2MB
  bf16* qbuf = (bf16*)(ws + 16 * MB);  // 8MB
  bf16* kbuf = (bf16*)(ws + 24 * MB);  // 8MB
  bf16* vTb  = (bf16*)(ws + 32 * MB);  // 8MB, [b][h][dk][s]
  bf16* abuf = (bf16*)(ws + 40 * MB);  // 8MB

  cvt5_kernel<<<8192, 256, 0, stream>>>(x, Wq, Wk, Wv, Wo, xb, wqb, wkb, wvb, wob);

  // fused QKV projection: N = 3072, 768 blocks
  gemm_nt<3><<<dim3(3072 / 128, 4096 / 128), 256, 0, stream>>>(
      xb, wqb, nullptr, qbuf, kbuf, vTb, 4096, 3072, 1024);

  attn_kernel<<<dim3(512), 512, 0, stream>>>(qbuf, kbuf, vTb, abuf);

  gemm_nt<0><<<dim3(1024 / 128, 4096 / 128), 256, 0, stream>>>(
      abuf, wob, out, nullptr, nullptr, nullptr, 4096, 1024, 1024);
}

// Round 9
// 176.162 us; speedup vs baseline: 1.6178x; 1.6178x over previous
//
#include <hip/hip_runtime.h>
#include <hip/hip_bf16.h>
#include <math.h>

typedef __bf16 bf16;
typedef __attribute__((ext_vector_type(8))) __bf16 bf16x8;
typedef __attribute__((ext_vector_type(4))) __bf16 bf16x4;
typedef __attribute__((ext_vector_type(4))) float f32x4;

#define NHEAD 16
#define DKH 64
#define SEQ 2048
#define DMODEL 1024

// async 16B global->LDS (wave-uniform LDS base + lane*16, per-lane global src)
__device__ __forceinline__ void gl_lds16(const void* g, void* lds) {
  __builtin_amdgcn_global_load_lds(
      (const __attribute__((address_space(1))) unsigned int*)g,
      (__attribute__((address_space(3))) unsigned int*)lds, 16, 0, 0);
}

// one launch converting x + 4 weight matrices fp32->bf16 (4-elem units)
__global__ void cvt5_kernel(const float* __restrict__ x, const float* __restrict__ wq,
                            const float* __restrict__ wk, const float* __restrict__ wv,
                            const float* __restrict__ wo, bf16* __restrict__ xb,
                            bf16* __restrict__ wqb, bf16* __restrict__ wkb,
                            bf16* __restrict__ wvb, bf16* __restrict__ wob) {
  int i = blockIdx.x * blockDim.x + threadIdx.x;  // [0, 2097152)
  const float* src; bf16* dst; int li;
  if (i < 1048576)      { src = x;  dst = xb;  li = i; }
  else if (i < 1310720) { src = wq; dst = wqb; li = i - 1048576; }
  else if (i < 1572864) { src = wk; dst = wkb; li = i - 1310720; }
  else if (i < 1835008) { src = wv; dst = wvb; li = i - 1572864; }
  else                  { src = wo; dst = wob; li = i - 1835008; }
  float4 v = ((const float4*)src)[li];
  bf16x4 o = { (bf16)v.x, (bf16)v.y, (bf16)v.z, (bf16)v.w };
  ((bf16x4*)dst)[li] = o;
}

// swizzled LDS fragment read, 64-col tiles (8 granules): granule ^= row&7
__device__ __forceinline__ bf16x8 lds_frag(const bf16* T, int row, int gran) {
  return *(const bf16x8*)&T[row * 64 + ((gran ^ (row & 7)) << 3)];
}
// swizzled LDS fragment read, 32-col tiles (4 granules): granule ^= row&3
__device__ __forceinline__ bf16x8 lds_frag32(const bf16* T, int row, int gran) {
  return *(const bf16x8*)&T[row * 32 + ((gran ^ (row & 3)) << 3)];
}

// C[m,n] = sum_k A[m,k]*B[n,k]; A:[M,K], B:[N,K] bf16 row-major. BK=32,
// double-buffered 2-phase (stage next -> compute cur -> one barrier), 32 KB
// LDS. NO forced min-occupancy: at ~88 VGPR the natural cap is 5 waves/SIMD,
// matching 5 blocks/CU LDS-wise (round-8's forced bound spilled acc to
// scratch: VGPR 48, WRITE_SIZE 10x). MODE 0: fp32 C. MODE 3: fused QKV split.
template<int MODE>
__global__ __launch_bounds__(256) void gemm_nt(const bf16* __restrict__ A,
                                               const bf16* __restrict__ Bw,
                                               float* __restrict__ Cf,
                                               bf16* __restrict__ Cq,
                                               bf16* __restrict__ Ck,
                                               bf16* __restrict__ Cv,
                                               int M, int N, int K) {
  __shared__ __attribute__((aligned(16))) bf16 As[2][128 * 32];
  __shared__ __attribute__((aligned(16))) bf16 Bs[2][128 * 32];
  const int t = threadIdx.x;
  const int w = t >> 6, l = t & 63;
  const int wr = w >> 1, wc = w & 1;
  // XCD-chunked swizzle (nwg divisible by 8): contiguous tile chunk per XCD
  const int lin = blockIdx.y * gridDim.x + blockIdx.x;
  const int cpx = (gridDim.x * gridDim.y) >> 3;
  const int swz = (lin & 7) * cpx + (lin >> 3);
  const int tm = (swz / gridDim.x) * 128, tn = (swz % gridDim.x) * 128;
  const int c16 = l & 15, g4 = l >> 4;
  const int srow = l >> 2;                       // 16 rows per gl_lds16
  const int sg = ((l & 3) ^ (srow & 3)) * 8;     // pre-swizzled src col (elems)

  f32x4 acc[4][4];
#pragma unroll
  for (int i = 0; i < 4; ++i)
#pragma unroll
    for (int j = 0; j < 4; ++j) acc[i][j] = f32x4{0.f, 0.f, 0.f, 0.f};

  auto stage = [&](int buf, int k0) {
#pragma unroll
    for (int c = 0; c < 2; ++c) {
      const int r0 = w * 32 + c * 16;  // wave-uniform segment base (16 rows)
      gl_lds16(A + (size_t)(tm + r0 + srow) * K + k0 + sg, &As[buf][r0 * 32]);
      gl_lds16(Bw + (size_t)(tn + r0 + srow) * K + k0 + sg, &Bs[buf][r0 * 32]);
    }
  };

  const int NK = K >> 5;
  stage(0, 0);
  __syncthreads();

  for (int kt = 0; kt < NK; ++kt) {
    const int cur = kt & 1;
    if (kt + 1 < NK) stage(cur ^ 1, (kt + 1) << 5);
    bf16x8 af[4], bfr[4];
#pragma unroll
    for (int i = 0; i < 4; ++i)
      af[i] = lds_frag32(As[cur], wr * 64 + i * 16 + c16, g4);
#pragma unroll
    for (int j = 0; j < 4; ++j)
      bfr[j] = lds_frag32(Bs[cur], wc * 64 + j * 16 + c16, g4);
    __builtin_amdgcn_s_setprio(1);
#pragma unroll
    for (int i = 0; i < 4; ++i)
#pragma unroll
      for (int j = 0; j < 4; ++j)
        acc[i][j] = __builtin_amdgcn_mfma_f32_16x16x32_bf16(af[i], bfr[j], acc[i][j], 0, 0, 0);
    __builtin_amdgcn_s_setprio(0);
    __syncthreads();  // drains prefetch vmcnt + everyone done reading cur
  }

  const int which = tn >> 10;  // MODE 3: whole block in one of q/k/v
#pragma unroll
  for (int i = 0; i < 4; ++i) {
    const int row0 = tm + wr * 64 + i * 16 + g4 * 4;
#pragma unroll
    for (int j = 0; j < 4; ++j) {
      const int col = tn + wc * 64 + j * 16 + c16;
      if (MODE == 0) {
#pragma unroll
        for (int r = 0; r < 4; ++r) Cf[(size_t)(row0 + r) * N + col] = acc[i][j][r];
      } else {
        const int lc = col & 1023;
        if (which == 2) {  // V: transposed per head
          const int bb = row0 >> 11, s = row0 & 2047;
          const int hh = lc >> 6, dk = lc & 63;
          bf16x4 o = { (bf16)acc[i][j][0], (bf16)acc[i][j][1],
                       (bf16)acc[i][j][2], (bf16)acc[i][j][3] };
          *(bf16x4*)&Cv[((size_t)(bb * NHEAD + hh) * DKH + dk) * SEQ + s] = o;
        } else {
          bf16* dst = which ? Ck : Cq;
#pragma unroll
          for (int r = 0; r < 4; ++r)
            dst[(size_t)(row0 + r) * DMODEL + lc] = (bf16)acc[i][j][r];
        }
      }
    }
  }
}

__device__ __forceinline__ f32x4 vmax4(f32x4 a, f32x4 b) {
  return f32x4{ fmaxf(a[0], b[0]), fmaxf(a[1], b[1]),
                fmaxf(a[2], b[2]), fmaxf(a[3], b[3]) };
}

// Flash attention, causal. 512 blocks x 512 threads (8 waves). Waves split in
// two groups: A (w<4) handles even 64-kv subtiles, B odd, of a staged 128-kv
// tile. Each block: q-tile pair (31-pr, pr) -> uniformly 17 iterations.
// Per-q-tile merge of (m,l,acc) through LDS (B -> A). Swapped QK^T, in-lane
// softmax, MFMA row-sum, defer-max.
__global__ __launch_bounds__(512, 4) void attn_kernel(const bf16* __restrict__ qb,
                                                      const bf16* __restrict__ kb,
                                                      const bf16* __restrict__ vT,
                                                      bf16* __restrict__ ob) {
  __shared__ __attribute__((aligned(16))) bf16 Ke[2][64 * 64];
  __shared__ __attribute__((aligned(16))) bf16 Ko[2][64 * 64];
  __shared__ __attribute__((aligned(16))) bf16 Ve[2][64 * 64];
  __shared__ __attribute__((aligned(16))) bf16 Vo[2][64 * 64];
  __shared__ __attribute__((aligned(16))) bf16 Pb[8][16 * 64];  // P + merge area
  const int w = threadIdx.x >> 6, l = threadIdx.x & 63;
  const int g = w >> 2, wq = w & 3;
  // bijective XCD chunking: 512 blocks, 64 consecutive work-items per XCD
  const int lin = blockIdx.x;
  const int swz = (lin & 7) * 64 + (lin >> 3);
  const int pr = swz & 15, h = (swz >> 4) & 15, b = swz >> 8;
  const int qtA = 31 - pr, qtB = pr;
  const int c16 = l & 15, g4 = l >> 4, r8 = l >> 3;
  const int sg = ((l & 7) ^ (r8 & 7)) * 8;  // pre-swizzled src col (elems)

  const float SC2 = 0.125f * 1.44269504089f;  // 1/sqrt(dk) * log2(e)
  const float THR = 8.0f / SC2;               // defer-max threshold (raw scores)

  const bf16 oneb = (bf16)1.0f;
  const bf16x8 ones = { oneb, oneb, oneb, oneb, oneb, oneb, oneb, oneb };

  const bf16* kbase = kb + (size_t)b * SEQ * DMODEL + h * DKH;
  const bf16* vbase = vT + (size_t)(b * NHEAD + h) * DKH * SEQ;

  // Q fragments (B-operand) for both q-tiles: row = qt*64 + wq*16 + c16
  bf16x8 qfA[2], qfB[2];
#pragma unroll
  for (int d = 0; d < 2; ++d) {
    qfA[d] = *(const bf16x8*)(qb + (size_t)(b * SEQ + qtA * 64 + wq * 16 + c16) * DMODEL +
                              h * DKH + d * 32 + g4 * 8);
    qfB[d] = *(const bf16x8*)(qb + (size_t)(b * SEQ + qtB * 64 + wq * 16 + c16) * DMODEL +
                              h * DKH + d * 32 + g4 * 8);
  }

  // stage a 128-kv tile (t128): 4 regions of 64x64, each wave does 8 rows each
  auto stage = [&](int buf, int t128) {
    const int kt0 = t128 * 128;
    const int row = w * 8;  // wave-uniform segment base
    gl_lds16(kbase + (size_t)(kt0 + row + r8) * DMODEL + sg, &Ke[buf][row * 64]);
    gl_lds16(kbase + (size_t)(kt0 + 64 + row + r8) * DMODEL + sg, &Ko[buf][row * 64]);
    gl_lds16(vbase + (size_t)(row + r8) * SEQ + kt0 + sg, &Ve[buf][row * 64]);
    gl_lds16(vbase + (size_t)(row + r8) * SEQ + kt0 + 64 + sg, &Vo[buf][row * 64]);
  };

  stage(0, 0);
  __syncthreads();

  float mm = -INFINITY;
  f32x4 lsum4 = f32x4{0.f, 0.f, 0.f, 0.f};
  f32x4 acc[4];
#pragma unroll
  for (int n = 0; n < 4; ++n) acc[n] = f32x4{0.f, 0.f, 0.f, 0.f};

  const int TA128 = (qtA + 2) >> 1;           // ceil((qtA+1)/2)
  const int TT128 = TA128 + ((qtB + 2) >> 1); // uniformly 17
  const int ql = wq * 16 + c16;               // q row local to 64-tile

  for (int tt = 0; tt < TT128; ++tt) {
    const int cur = tt & 1;
    if (tt + 1 < TT128)
      stage(cur ^ 1, (tt + 1 < TA128) ? tt + 1 : tt + 1 - TA128);
    const bool pA = tt < TA128;
    const int t_in = pA ? tt : tt - TA128;
    const int qt = pA ? qtA : qtB;
    const int kt64 = 2 * t_in + g;  // this group's 64-kv subtile index

    if (kt64 <= qt) {
      const bf16* Kl = g ? &Ko[cur][0] : &Ke[cur][0];
      const bf16* Vl = g ? &Vo[cur][0] : &Ve[cur][0];
      const bf16x8 q0 = pA ? qfA[0] : qfB[0];
      const bf16x8 q1 = pA ? qfA[1] : qfB[1];

      // ---- QK^T swapped (raw): s[j] rows kv = j*16+g4*4+r, cols q = c16
      f32x4 s[4];
      __builtin_amdgcn_s_setprio(1);
#pragma unroll
      for (int j = 0; j < 4; ++j) {
        bf16x8 kf0 = lds_frag(Kl, j * 16 + c16, g4);
        bf16x8 kf1 = lds_frag(Kl, j * 16 + c16, 4 + g4);
        f32x4 c = f32x4{0.f, 0.f, 0.f, 0.f};
        c = __builtin_amdgcn_mfma_f32_16x16x32_bf16(kf0, q0, c, 0, 0, 0);
        c = __builtin_amdgcn_mfma_f32_16x16x32_bf16(kf1, q1, c, 0, 0, 0);
        s[j] = c;
      }
      __builtin_amdgcn_s_setprio(0);
      if (kt64 == qt) {  // diagonal subtile
#pragma unroll
        for (int j = 0; j < 4; ++j)
#pragma unroll
          for (int r = 0; r < 4; ++r)
            if (j * 16 + g4 * 4 + r > ql) s[j][r] = -INFINITY;
      }
      // ---- tile max of the 16 in-lane scores + 2 shfl
      f32x4 t01 = vmax4(s[0], s[1]);
      f32x4 t23 = vmax4(s[2], s[3]);
      f32x4 tv = vmax4(t01, t23);
      float v = fmaxf(fmaxf(tv[0], tv[1]), fmaxf(tv[2], tv[3]));
      v = fmaxf(v, __shfl_xor(v, 16));
      v = fmaxf(v, __shfl_xor(v, 32));
      // ---- defer-max: skip rescale when bounded (p <= 2^8)
      if (!__all(v <= mm + THR)) {
        const float mn = fmaxf(mm, v);
        const float scl = __builtin_amdgcn_exp2f(SC2 * (mm - mn));
        float sc4[4];
#pragma unroll
        for (int r = 0; r < 4; ++r) sc4[r] = __shfl(scl, g4 * 4 + r);
#pragma unroll
        for (int n = 0; n < 4; ++n)
#pragma unroll
          for (int r = 0; r < 4; ++r) acc[n][r] *= sc4[r];
#pragma unroll
        for (int r = 0; r < 4; ++r) lsum4[r] *= sc4[r];
        mm = mn;
      }
      const float nb = SC2 * mm;
      // ---- exp + spill P (b64 per 4 consecutive kv)
      bf16* P = &Pb[w][0];
#pragma unroll
      for (int j = 0; j < 4; ++j) {
        bf16x4 pk;
#pragma unroll
        for (int r = 0; r < 4; ++r)
          pk[r] = (bf16)__builtin_amdgcn_exp2f(fmaf(s[j][r], SC2, -nb));
        const int col = j * 16 + g4 * 4;
        *(bf16x4*)&P[c16 * 64 + (((col >> 3) ^ (c16 & 7)) << 3) + (col & 7)] = pk;
      }
      // ---- PV + row-sum via MFMA
      bf16x8 pa0 = lds_frag(P, c16, g4);
      bf16x8 pa1 = lds_frag(P, c16, 4 + g4);
      __builtin_amdgcn_s_setprio(1);
#pragma unroll
      for (int n = 0; n < 4; ++n) {
        bf16x8 vf0 = lds_frag(Vl, n * 16 + c16, g4);
        bf16x8 vf1 = lds_frag(Vl, n * 16 + c16, 4 + g4);
        acc[n] = __builtin_amdgcn_mfma_f32_16x16x32_bf16(pa0, vf0, acc[n], 0, 0, 0);
        acc[n] = __builtin_amdgcn_mfma_f32_16x16x32_bf16(pa1, vf1, acc[n], 0, 0, 0);
      }
      lsum4 = __builtin_amdgcn_mfma_f32_16x16x32_bf16(pa0, ones, lsum4, 0, 0, 0);
      lsum4 = __builtin_amdgcn_mfma_f32_16x16x32_bf16(pa1, ones, lsum4, 0, 0, 0);
      __builtin_amdgcn_s_setprio(0);
    }

    const bool mergeA = (tt == TA128 - 1);
    const bool mergeB = (tt == TT128 - 1);
    if (mergeA || mergeB) {
      const int qb0 = (mergeA ? qtA : qtB) * 64;
      __syncthreads();  // all compute done; P slots free for merge reuse
      float* ml = (float*)&Pb[wq][0];   // [0..15]=mB per q-row, [16..31]=lB
      bf16* xa = &Pb[4 + wq][0];        // accB bf16 [16 q][64 cols]
      if (g == 1) {
        if (g4 == 0) ml[c16] = mm;
        if (c16 == 0) {
#pragma unroll
          for (int r = 0; r < 4; ++r) ml[16 + g4 * 4 + r] = lsum4[r];
        }
#pragma unroll
        for (int n = 0; n < 4; ++n)
#pragma unroll
          for (int r = 0; r < 4; ++r)
            xa[(g4 * 4 + r) * 64 + n * 16 + c16] = (bf16)acc[n][r];
      }
      __syncthreads();  // B's state visible
      if (g == 0) {
#pragma unroll
        for (int r = 0; r < 4; ++r) {
          const int q = g4 * 4 + r;
          const float mA = __shfl(mm, q);
          const float mB = ml[q];
          const float lB = ml[16 + q];
          const float mt = fmaxf(mA, mB);
          const float fA = __builtin_amdgcn_exp2f(SC2 * (mA - mt));
          const float fB = __builtin_amdgcn_exp2f(SC2 * (mB - mt));
          const float inv = 1.f / (lsum4[r] * fA + lB * fB);
#pragma unroll
          for (int n = 0; n < 4; ++n) {
            const float accB = (float)xa[q * 64 + n * 16 + c16];
            const float o = (acc[n][r] * fA + accB * fB) * inv;
            ob[(size_t)(b * SEQ + qb0 + wq * 16 + q) * DMODEL +
               h * DKH + n * 16 + c16] = (bf16)o;
          }
        }
      }
      // reset both groups for next q-tile
      mm = -INFINITY;
      lsum4 = f32x4{0.f, 0.f, 0.f, 0.f};
#pragma unroll
      for (int n = 0; n < 4; ++n) acc[n] = f32x4{0.f, 0.f, 0.f, 0.f};
    }
    __syncthreads();  // protects P rewrite + dbuf flip (also after merge reads)
  }
}

extern "C" void kernel_launch(void* const* d_in, const int* in_sizes, int n_in,
                              void* d_out, int out_size, void* d_ws, size_t ws_size,
                              hipStream_t stream) {
  const float* x  = (const float*)d_in[0];
  const float* Wq = (const float*)d_in[1];
  const float* Wk = (const float*)d_in[2];
  const float* Wv = (const float*)d_in[3];
  const float* Wo = (const float*)d_in[4];
  float* out = (float*)d_out;
  char* ws = (char*)d_ws;
  const size_t MB = (size_t)1 << 20;

  // wqb/wkb/wvb contiguous -> one [3072][1024] weight matrix for fused QKV
  bf16* xb   = (bf16*)(ws + 0 * MB);   // 8MB
  bf16* wqb  = (bf16*)(ws + 8 * MB);   // 2MB
  bf16* wkb  = (bf16*)(ws + 10 * MB);  // 2MB
  bf16* wvb  = (bf16*)(ws + 12 * MB);  // 2MB
  bf16* wob  = (bf16*)(ws + 14 * MB);  // 2MB
  bf16* qbuf = (bf16*)(ws + 16 * MB);  // 8MB
  bf16* kbuf = (bf16*)(ws + 24 * MB);  // 8MB
  bf16* vTb  = (bf16*)(ws + 32 * MB);  // 8MB, [b][h][dk][s]
  bf16* abuf = (bf16*)(ws + 40 * MB);  // 8MB

  cvt5_kernel<<<8192, 256, 0, stream>>>(x, Wq, Wk, Wv, Wo, xb, wqb, wkb, wvb, wob);

  // fused QKV projection: N = 3072, 768 blocks
  gemm_nt<3><<<dim3(3072 / 128, 4096 / 128), 256, 0, stream>>>(
      xb, wqb, nullptr, qbuf, kbuf, vTb, 4096, 3072, 1024);

  attn_kernel<<<dim3(512), 512, 0, stream>>>(qbuf, kbuf, vTb, abuf);

  gemm_nt<0><<<dim3(1024 / 128, 4096 / 128), 256, 0, stream>>>(
      abuf, wob, out, nullptr, nullptr, nullptr, 4096, 1024, 1024);
}

// Round 10
// 174.398 us; speedup vs baseline: 1.6341x; 1.0101x over previous
//
#include <hip/hip_runtime.h>
#include <hip/hip_bf16.h>
#include <math.h>

typedef __bf16 bf16;
typedef __attribute__((ext_vector_type(8))) __bf16 bf16x8;
typedef __attribute__((ext_vector_type(4))) __bf16 bf16x4;
typedef __attribute__((ext_vector_type(4))) float f32x4;

#define NHEAD 16
#define DKH 64
#define SEQ 2048
#define DMODEL 1024

// async 16B global->LDS (wave-uniform LDS base + lane*16, per-lane global src)
__device__ __forceinline__ void gl_lds16(const void* g, void* lds) {
  __builtin_amdgcn_global_load_lds(
      (const __attribute__((address_space(1))) unsigned int*)g,
      (__attribute__((address_space(3))) unsigned int*)lds, 16, 0, 0);
}

// one launch converting x + 4 weight matrices fp32->bf16 (4-elem units)
__global__ void cvt5_kernel(const float* __restrict__ x, const float* __restrict__ wq,
                            const float* __restrict__ wk, const float* __restrict__ wv,
                            const float* __restrict__ wo, bf16* __restrict__ xb,
                            bf16* __restrict__ wqb, bf16* __restrict__ wkb,
                            bf16* __restrict__ wvb, bf16* __restrict__ wob) {
  int i = blockIdx.x * blockDim.x + threadIdx.x;  // [0, 2097152)
  const float* src; bf16* dst; int li;
  if (i < 1048576)      { src = x;  dst = xb;  li = i; }
  else if (i < 1310720) { src = wq; dst = wqb; li = i - 1048576; }
  else if (i < 1572864) { src = wk; dst = wkb; li = i - 1310720; }
  else if (i < 1835008) { src = wv; dst = wvb; li = i - 1572864; }
  else                  { src = wo; dst = wob; li = i - 1835008; }
  float4 v = ((const float4*)src)[li];
  bf16x4 o = { (bf16)v.x, (bf16)v.y, (bf16)v.z, (bf16)v.w };
  ((bf16x4*)dst)[li] = o;
}

// C[m,n] = sum_k A[m,k]*B[n,k]; A:[M,K], B:[N,K] bf16 row-major. BK=32, dbuf
// 2-phase. LDS tile stored in PHYSICAL [64][64] layout (logical row r,k ->
// phys row r>>1, col (r&1)*32+k) so reads use the conflict-free 64-col XOR
// swizzle (r8's 32-col layout was ~8-way conflicted: 3.1M SQ_LDS_BANK_CONFLICT).
// All LDS/global addresses hoisted to per-lane loop-invariant bases.
// MODE 0: fp32 C. MODE 3: fused QKV split.
template<int MODE>
__global__ __launch_bounds__(256) void gemm_nt(const bf16* __restrict__ A,
                                               const bf16* __restrict__ Bw,
                                               float* __restrict__ Cf,
                                               bf16* __restrict__ Cq,
                                               bf16* __restrict__ Ck,
                                               bf16* __restrict__ Cv,
                                               int M, int N, int K) {
  __shared__ __attribute__((aligned(16))) bf16 As[2][64 * 64];  // 16 KB
  __shared__ __attribute__((aligned(16))) bf16 Bs[2][64 * 64];  // 16 KB
  const int t = threadIdx.x;
  const int w = t >> 6, l = t & 63;
  const int wr = w >> 1, wc = w & 1;
  // XCD-chunked swizzle (nwg divisible by 8): contiguous tile chunk per XCD
  const int lin = blockIdx.y * gridDim.x + blockIdx.x;
  const int cpx = (gridDim.x * gridDim.y) >> 3;
  const int swz = (lin & 7) * cpx + (lin >> 3);
  const int tm = (swz / gridDim.x) * 128, tn = (swz % gridDim.x) * 128;
  const int c16 = l & 15, g4 = l >> 4;

  // ---- staging decode (loop-invariant): lane l of chunk c writes phys row
  // w*16 + c*8 + (l>>3), stored granule l&7; logical granule = (l&7)^(l>>3).
  const int gl0 = (l & 7) ^ (l >> 3);
  const int kgr8 = (gl0 & 3) * 8;           // k offset within BK=32
  const int rL0 = (w * 16 + (l >> 3)) * 2 + (gl0 >> 2);      // c=0 logical row
  const int rL1 = (w * 16 + 8 + (l >> 3)) * 2 + (gl0 >> 2);  // c=1 logical row
  const size_t srcA0 = (size_t)(tm + rL0) * K + kgr8;
  const size_t srcA1 = (size_t)(tm + rL1) * K + kgr8;
  const size_t srcB0 = (size_t)(tn + rL0) * K + kgr8;
  const size_t srcB1 = (size_t)(tn + rL1) * K + kgr8;
  // ---- read offset (bytes, loop-invariant): logical row base + c16, gran g4
  const int laneRd = (c16 >> 1) * 128 +
                     ((((c16 & 1) * 4 + g4) ^ ((c16 >> 1) & 7)) << 4);
  const int rdA = wr * 4096 + laneRd;
  const int rdB = wc * 4096 + laneRd;

  f32x4 acc[4][4];
#pragma unroll
  for (int i = 0; i < 4; ++i)
#pragma unroll
    for (int j = 0; j < 4; ++j) acc[i][j] = f32x4{0.f, 0.f, 0.f, 0.f};

  auto stage = [&](int buf, int k0) {
    gl_lds16(A + srcA0 + k0, &As[buf][(w * 16) * 64]);
    gl_lds16(A + srcA1 + k0, &As[buf][(w * 16 + 8) * 64]);
    gl_lds16(Bw + srcB0 + k0, &Bs[buf][(w * 16) * 64]);
    gl_lds16(Bw + srcB1 + k0, &Bs[buf][(w * 16 + 8) * 64]);
  };

  const int NK = K >> 5;
  stage(0, 0);
  __syncthreads();

  for (int kt = 0; kt < NK; ++kt) {
    const int cur = kt & 1;
    if (kt + 1 < NK) stage(cur ^ 1, (kt + 1) << 5);
    const char* Ab = (const char*)&As[cur][0];
    const char* Bb = (const char*)&Bs[cur][0];
    bf16x8 af[4], bfr[4];
#pragma unroll
    for (int i = 0; i < 4; ++i) af[i] = *(const bf16x8*)(Ab + rdA + i * 1024);
#pragma unroll
    for (int j = 0; j < 4; ++j) bfr[j] = *(const bf16x8*)(Bb + rdB + j * 1024);
    __builtin_amdgcn_s_setprio(1);
#pragma unroll
    for (int i = 0; i < 4; ++i)
#pragma unroll
      for (int j = 0; j < 4; ++j)
        acc[i][j] = __builtin_amdgcn_mfma_f32_16x16x32_bf16(af[i], bfr[j], acc[i][j], 0, 0, 0);
    __builtin_amdgcn_s_setprio(0);
    __syncthreads();  // drains prefetch vmcnt + everyone done reading cur
  }

  const int which = tn >> 10;  // MODE 3: whole block in one of q/k/v
#pragma unroll
  for (int i = 0; i < 4; ++i) {
    const int row0 = tm + wr * 64 + i * 16 + g4 * 4;
#pragma unroll
    for (int j = 0; j < 4; ++j) {
      const int col = tn + wc * 64 + j * 16 + c16;
      if (MODE == 0) {
#pragma unroll
        for (int r = 0; r < 4; ++r) Cf[(size_t)(row0 + r) * N + col] = acc[i][j][r];
      } else {
        const int lc = col & 1023;
        if (which == 2) {  // V: transposed per head
          const int bb = row0 >> 11, s = row0 & 2047;
          const int hh = lc >> 6, dk = lc & 63;
          bf16x4 o = { (bf16)acc[i][j][0], (bf16)acc[i][j][1],
                       (bf16)acc[i][j][2], (bf16)acc[i][j][3] };
          *(bf16x4*)&Cv[((size_t)(bb * NHEAD + hh) * DKH + dk) * SEQ + s] = o;
        } else {
          bf16* dst = which ? Ck : Cq;
#pragma unroll
          for (int r = 0; r < 4; ++r)
            dst[(size_t)(row0 + r) * DMODEL + lc] = (bf16)acc[i][j][r];
        }
      }
    }
  }
}

__device__ __forceinline__ f32x4 vmax4(f32x4 a, f32x4 b) {
  return f32x4{ fmaxf(a[0], b[0]), fmaxf(a[1], b[1]),
                fmaxf(a[2], b[2]), fmaxf(a[3], b[3]) };
}

// Flash attention, causal. 512 blocks x 512 threads (8 waves, 2 kv-groups).
// Same structure as round 9; all LDS swizzle addresses hoisted to per-lane
// loop-invariant byte offsets (row&7 == c16&7 for every tile row stride).
__global__ __launch_bounds__(512, 4) void attn_kernel(const bf16* __restrict__ qb,
                                                      const bf16* __restrict__ kb,
                                                      const bf16* __restrict__ vT,
                                                      bf16* __restrict__ ob) {
  __shared__ __attribute__((aligned(16))) bf16 Ke[2][64 * 64];
  __shared__ __attribute__((aligned(16))) bf16 Ko[2][64 * 64];
  __shared__ __attribute__((aligned(16))) bf16 Ve[2][64 * 64];
  __shared__ __attribute__((aligned(16))) bf16 Vo[2][64 * 64];
  __shared__ __attribute__((aligned(16))) bf16 Pb[8][16 * 64];  // P + merge area
  const int w = threadIdx.x >> 6, l = threadIdx.x & 63;
  const int g = w >> 2, wq = w & 3;
  // bijective XCD chunking: 512 blocks, 64 consecutive work-items per XCD
  const int lin = blockIdx.x;
  const int swz = (lin & 7) * 64 + (lin >> 3);
  const int pr = swz & 15, h = (swz >> 4) & 15, b = swz >> 8;
  const int qtA = 31 - pr, qtB = pr;
  const int c16 = l & 15, g4 = l >> 4, r8 = l >> 3;
  const int sg = ((l & 7) ^ (r8 & 7)) * 8;  // pre-swizzled src col (elems)

  const float SC2 = 0.125f * 1.44269504089f;  // 1/sqrt(dk) * log2(e)
  const float THR = 8.0f / SC2;               // defer-max threshold (raw scores)

  const bf16 oneb = (bf16)1.0f;
  const bf16x8 ones = { oneb, oneb, oneb, oneb, oneb, oneb, oneb, oneb };

  const bf16* kbase = kb + (size_t)b * SEQ * DMODEL + h * DKH;
  const bf16* vbase = vT + (size_t)(b * NHEAD + h) * DKH * SEQ;

  // hoisted LDS read offsets (bytes): row stride 128 B, granule XOR by c16&7
  const int loK = c16 * 128 + ((g4 ^ (c16 & 7)) << 4);  // lo granule; hi = ^64
  // hoisted P-write offset: col = j*16+g4*4 -> swz = base ^ (j<<5)
  const int pW = c16 * 128 + ((((g4 >> 1) ^ (c16 & 7)) << 4)) + (g4 & 1) * 8;
  // hoisted stage source offsets (elems)
  const size_t kSrc = (size_t)(w * 8 + r8) * DMODEL + sg;
  const size_t vSrc = (size_t)(w * 8 + r8) * SEQ + sg;

  // Q fragments (B-operand) for both q-tiles: row = qt*64 + wq*16 + c16
  bf16x8 qfA[2], qfB[2];
#pragma unroll
  for (int d = 0; d < 2; ++d) {
    qfA[d] = *(const bf16x8*)(qb + (size_t)(b * SEQ + qtA * 64 + wq * 16 + c16) * DMODEL +
                              h * DKH + d * 32 + g4 * 8);
    qfB[d] = *(const bf16x8*)(qb + (size_t)(b * SEQ + qtB * 64 + wq * 16 + c16) * DMODEL +
                              h * DKH + d * 32 + g4 * 8);
  }

  // stage a 128-kv tile (t128): 4 regions of 64x64, each wave does 8 rows each
  auto stage = [&](int buf, int t128) {
    const size_t kt0 = (size_t)t128 * 128;
    gl_lds16(kbase + kSrc + kt0 * DMODEL, &Ke[buf][w * 8 * 64]);
    gl_lds16(kbase + kSrc + (kt0 + 64) * DMODEL, &Ko[buf][w * 8 * 64]);
    gl_lds16(vbase + vSrc + kt0, &Ve[buf][w * 8 * 64]);
    gl_lds16(vbase + vSrc + kt0 + 64, &Vo[buf][w * 8 * 64]);
  };

  stage(0, 0);
  __syncthreads();

  float mm = -INFINITY;
  f32x4 lsum4 = f32x4{0.f, 0.f, 0.f, 0.f};
  f32x4 acc[4];
#pragma unroll
  for (int n = 0; n < 4; ++n) acc[n] = f32x4{0.f, 0.f, 0.f, 0.f};

  const int TA128 = (qtA + 2) >> 1;           // ceil((qtA+1)/2)
  const int TT128 = TA128 + ((qtB + 2) >> 1); // uniformly 17
  const int ql = wq * 16 + c16;               // q row local to 64-tile

  for (int tt = 0; tt < TT128; ++tt) {
    const int cur = tt & 1;
    if (tt + 1 < TT128)
      stage(cur ^ 1, (tt + 1 < TA128) ? tt + 1 : tt + 1 - TA128);
    const bool pA = tt < TA128;
    const int t_in = pA ? tt : tt - TA128;
    const int qt = pA ? qtA : qtB;
    const int kt64 = 2 * t_in + g;  // this group's 64-kv subtile index

    if (kt64 <= qt) {
      const char* Kl = (const char*)(g ? &Ko[cur][0] : &Ke[cur][0]);
      const char* Vl = (const char*)(g ? &Vo[cur][0] : &Ve[cur][0]);
      const bf16x8 q0 = pA ? qfA[0] : qfB[0];
      const bf16x8 q1 = pA ? qfA[1] : qfB[1];

      // ---- QK^T swapped (raw): s[j] rows kv = j*16+g4*4+r, cols q = c16
      f32x4 s[4];
      __builtin_amdgcn_s_setprio(1);
#pragma unroll
      for (int j = 0; j < 4; ++j) {
        bf16x8 kf0 = *(const bf16x8*)(Kl + loK + j * 2048);
        bf16x8 kf1 = *(const bf16x8*)(Kl + (loK ^ 64) + j * 2048);
        f32x4 c = f32x4{0.f, 0.f, 0.f, 0.f};
        c = __builtin_amdgcn_mfma_f32_16x16x32_bf16(kf0, q0, c, 0, 0, 0);
        c = __builtin_amdgcn_mfma_f32_16x16x32_bf16(kf1, q1, c, 0, 0, 0);
        s[j] = c;
      }
      __builtin_amdgcn_s_setprio(0);
      if (kt64 == qt) {  // diagonal subtile
#pragma unroll
        for (int j = 0; j < 4; ++j)
#pragma unroll
          for (int r = 0; r < 4; ++r)
            if (j * 16 + g4 * 4 + r > ql) s[j][r] = -INFINITY;
      }
      // ---- tile max of the 16 in-lane scores + 2 shfl
      f32x4 t01 = vmax4(s[0], s[1]);
      f32x4 t23 = vmax4(s[2], s[3]);
      f32x4 tv = vmax4(t01, t23);
      float v = fmaxf(fmaxf(tv[0], tv[1]), fmaxf(tv[2], tv[3]));
      v = fmaxf(v, __shfl_xor(v, 16));
      v = fmaxf(v, __shfl_xor(v, 32));
      // ---- defer-max: skip rescale when bounded (p <= 2^8)
      if (!__all(v <= mm + THR)) {
        const float mn = fmaxf(mm, v);
        const float scl = __builtin_amdgcn_exp2f(SC2 * (mm - mn));
        float sc4[4];
#pragma unroll
        for (int r = 0; r < 4; ++r) sc4[r] = __shfl(scl, g4 * 4 + r);
#pragma unroll
        for (int n = 0; n < 4; ++n)
#pragma unroll
          for (int r = 0; r < 4; ++r) acc[n][r] *= sc4[r];
#pragma unroll
        for (int r = 0; r < 4; ++r) lsum4[r] *= sc4[r];
        mm = mn;
      }
      const float nb = SC2 * mm;
      // ---- exp + spill P (b64 per 4 consecutive kv)
      char* P = (char*)&Pb[w][0];
#pragma unroll
      for (int j = 0; j < 4; ++j) {
        bf16x4 pk;
#pragma unroll
        for (int r = 0; r < 4; ++r)
          pk[r] = (bf16)__builtin_amdgcn_exp2f(fmaf(s[j][r], SC2, -nb));
        *(bf16x4*)(P + (pW ^ (j << 5))) = pk;
      }
      // ---- PV + row-sum via MFMA
      bf16x8 pa0 = *(const bf16x8*)(P + loK);
      bf16x8 pa1 = *(const bf16x8*)(P + (loK ^ 64));
      __builtin_amdgcn_s_setprio(1);
#pragma unroll
      for (int n = 0; n < 4; ++n) {
        bf16x8 vf0 = *(const bf16x8*)(Vl + loK + n * 2048);
        bf16x8 vf1 = *(const bf16x8*)(Vl + (loK ^ 64) + n * 2048);
        acc[n] = __builtin_amdgcn_mfma_f32_16x16x32_bf16(pa0, vf0, acc[n], 0, 0, 0);
        acc[n] = __builtin_amdgcn_mfma_f32_16x16x32_bf16(pa1, vf1, acc[n], 0, 0, 0);
      }
      lsum4 = __builtin_amdgcn_mfma_f32_16x16x32_bf16(pa0, ones, lsum4, 0, 0, 0);
      lsum4 = __builtin_amdgcn_mfma_f32_16x16x32_bf16(pa1, ones, lsum4, 0, 0, 0);
      __builtin_amdgcn_s_setprio(0);
    }

    const bool mergeA = (tt == TA128 - 1);
    const bool mergeB = (tt == TT128 - 1);
    if (mergeA || mergeB) {
      const int qb0 = (mergeA ? qtA : qtB) * 64;
      __syncthreads();  // all compute done; P slots free for merge reuse
      float* ml = (float*)&Pb[wq][0];   // [0..15]=mB per q-row, [16..31]=lB
      bf16* xa = &Pb[4 + wq][0];        // accB bf16 [16 q][64 cols]
      if (g == 1) {
        if (g4 == 0) ml[c16] = mm;
        if (c16 == 0) {
#pragma unroll
          for (int r = 0; r < 4; ++r) ml[16 + g4 * 4 + r] = lsum4[r];
        }
#pragma unroll
        for (int n = 0; n < 4; ++n)
#pragma unroll
          for (int r = 0; r < 4; ++r)
            xa[(g4 * 4 + r) * 64 + n * 16 + c16] = (bf16)acc[n][r];
      }
      __syncthreads();  // B's state visible
      if (g == 0) {
#pragma unroll
        for (int r = 0; r < 4; ++r) {
          const int q = g4 * 4 + r;
          const float mA = __shfl(mm, q);
          const float mB = ml[q];
          const float lB = ml[16 + q];
          const float mt = fmaxf(mA, mB);
          const float fA = __builtin_amdgcn_exp2f(SC2 * (mA - mt));
          const float fB = __builtin_amdgcn_exp2f(SC2 * (mB - mt));
          const float inv = 1.f / (lsum4[r] * fA + lB * fB);
#pragma unroll
          for (int n = 0; n < 4; ++n) {
            const float accB = (float)xa[q * 64 + n * 16 + c16];
            const float o = (acc[n][r] * fA + accB * fB) * inv;
            ob[(size_t)(b * SEQ + qb0 + wq * 16 + q) * DMODEL +
               h * DKH + n * 16 + c16] = (bf16)o;
          }
        }
      }
      // reset both groups for next q-tile
      mm = -INFINITY;
      lsum4 = f32x4{0.f, 0.f, 0.f, 0.f};
#pragma unroll
      for (int n = 0; n < 4; ++n) acc[n] = f32x4{0.f, 0.f, 0.f, 0.f};
    }
    __syncthreads();  // protects P rewrite + dbuf flip (also after merge reads)
  }
}

extern "C" void kernel_launch(void* const* d_in, const int* in_sizes, int n_in,
                              void* d_out, int out_size, void* d_ws, size_t ws_size,
                              hipStream_t stream) {
  const float* x  = (const float*)d_in[0];
  const float* Wq = (const float*)d_in[1];
  const float* Wk = (const float*)d_in[2];
  const float* Wv = (const float*)d_in[3];
  const float* Wo = (const float*)d_in[4];
  float* out = (float*)d_out;
  char* ws = (char*)d_ws;
  const size_t MB = (size_t)1 << 20;

  // wqb/wkb/wvb contiguous -> one [3072][1024] weight matrix for fused QKV
  bf16* xb   = (bf16*)(ws + 0 * MB);   // 8MB
  bf16* wqb  = (bf16*)(ws + 8 * MB);   // 2MB
  bf16* wkb  = (bf16*)(ws + 10 * MB);  // 2MB
  bf16* wvb  = (bf16*)(ws + 12 * MB);  // 2MB
  bf16* wob  = (bf16*)(ws + 14 * MB);  // 2MB
  bf16* qbuf = (bf16*)(ws + 16 * MB);  // 8MB
  bf16* kbuf = (bf16*)(ws + 24 * MB);  // 8MB
  bf16* vTb  = (bf16*)(ws + 32 * MB);  // 8MB, [b][h][dk][s]
  bf16* abuf = (bf16*)(ws + 40 * MB);  // 8MB

  cvt5_kernel<<<8192, 256, 0, stream>>>(x, Wq, Wk, Wv, Wo, xb, wqb, wkb, wvb, wob);

  // fused QKV projection: N = 3072, 768 blocks
  gemm_nt<3><<<dim3(3072 / 128, 4096 / 128), 256, 0, stream>>>(
      xb, wqb, nullptr, qbuf, kbuf, vTb, 4096, 3072, 1024);

  attn_kernel<<<dim3(512), 512, 0, stream>>>(qbuf, kbuf, vTb, abuf);

  gemm_nt<0><<<dim3(1024 / 128, 4096 / 128), 256, 0, stream>>>(
      abuf, wob, out, nullptr, nullptr, nullptr, 4096, 1024, 1024);
}